// Round 7
// baseline (39.107 us; speedup 1.0000x reference)
//
#include <hip/hip_runtime.h>

#define CV_H 96
#define CV_W 128
#define CV_C 16
#define CV_K 7
#define CV_D 64
#define CV_EPS 1e-8f
#define CV_HW (CV_H * CV_W)
#define LDS_V8H 2560           // 40 KB staging budget (v8h = 16 B units)

typedef _Float16 v2h __attribute__((ext_vector_type(2)));
typedef _Float16 v8h __attribute__((ext_vector_type(8)));

#if __has_builtin(__builtin_amdgcn_fdot2)
#define FDOT2(a, b, c) __builtin_amdgcn_fdot2((a), (b), (c), false)
#else
#define FDOT2(a, b, c) ((float)(a)[0] * (float)(b)[0] + (float)(a)[1] * (float)(b)[1] + (c))
#endif

// ---------------------------------------------------------------------------
// Prep (round-3 proven): blocks 0..(K+1)*H-1 LDS-transpose one (view,row)
// [C=16][W=128] f32 -> [W][C] fp16.  Last block: depth planes + fused
// projection matrices M[k]=[A|b]; cam = depth*(A@[x+.5,y+.5,1]) + b.
// ---------------------------------------------------------------------------
__global__ __launch_bounds__(256) void cv_prep(
    const float* __restrict__ cur, const float* __restrict__ src,
    const float* __restrict__ extr, const float* __restrict__ Ks,
    const float* __restrict__ invK, const float* __restrict__ minD,
    const float* __restrict__ maxD,
    float* __restrict__ depths, float* __restrict__ M,
    _Float16* __restrict__ srcT, _Float16* __restrict__ curT) {
    const int b = blockIdx.x;
    if (b == (CV_K + 1) * CV_H) {
        int t = threadIdx.x;
        if (t < CV_D) {
            float mn = minD[0], mx = maxD[0];
            float ramp = (float)t * (1.0f / (CV_D - 1));
            depths[t] = expf(logf(mn) + logf(mx / mn) * ramp);
        }
        if (t < CV_K) {
            const float* Km = Ks + t * 16;
            const float* E  = extr + t * 16;
            float P[3][4];
            for (int i = 0; i < 3; ++i)
                for (int j = 0; j < 4; ++j) {
                    float s = 0.f;
                    for (int l = 0; l < 4; ++l) s += Km[i * 4 + l] * E[l * 4 + j];
                    P[i][j] = s;
                }
            float* Mk = M + t * 12;
            for (int i = 0; i < 3; ++i)
                for (int j = 0; j < 3; ++j) {
                    float s = 0.f;
                    for (int l = 0; l < 3; ++l) s += P[i][l] * invK[l * 4 + j];
                    Mk[i * 3 + j] = s;
                }
            for (int i = 0; i < 3; ++i) Mk[9 + i] = P[i][3];
        }
        return;
    }
    const int g = b / CV_H;
    const int h = b % CV_H;
    const float* rowBase = (g < CV_K) ? (src + (size_t)g * CV_C * CV_HW + h * CV_W)
                                      : (cur + h * CV_W);
    __shared__ float lds[CV_C][CV_W + 2];
    const int t = threadIdx.x;
#pragma unroll
    for (int i = 0; i < 2; ++i) {
        int f  = t + i * 256;
        int c  = f >> 5;
        int w4 = (f & 31) << 2;
        float4 v = *(const float4*)(rowBase + (size_t)c * CV_HW + w4);
        lds[c][w4 + 0] = v.x; lds[c][w4 + 1] = v.y;
        lds[c][w4 + 2] = v.z; lds[c][w4 + 3] = v.w;
    }
    __syncthreads();
    const int p  = t >> 1;
    const int cb = (t & 1) << 3;
    v8h o;
#pragma unroll
    for (int j = 0; j < 8; ++j) o[j] = (_Float16)lds[cb + j][p];
    _Float16* dst = (g < CV_K)
        ? (srcT + ((size_t)g * CV_HW + h * CV_W + p) * CV_C + cb)
        : (curT + ((size_t)h * CV_W + p) * CV_C + cb);
    *(v8h*)dst = o;
}

__device__ __forceinline__ float dot16h(v8h a0, v8h a1, v8h b0, v8h b1) {
    const v2h* pa0 = (const v2h*)&a0; const v2h* pb0 = (const v2h*)&b0;
    const v2h* pa1 = (const v2h*)&a1; const v2h* pb1 = (const v2h*)&b1;
    float s = 0.f;
#pragma unroll
    for (int i = 0; i < 4; ++i) s = FDOT2(pa0[i], pb0[i], s);
#pragma unroll
    for (int i = 0; i < 4; ++i) s = FDOT2(pa1[i], pb1[i], s);
    return s;
}

// ---------------------------------------------------------------------------
// Main: block = 8x8 px tile x 16 depths, 4 depths/thread.  Per view:
// (1) bbox of the 8 projected tile-corner points (4 corners x {d_lo,d_hi}).
//     All samples lie in its hull (ray projects to a line; z multilinear
//     over the (px,py,d) box, so corner z>0 => interior z>0).
// (2) If bbox fits 40 KB and z-safe: stage band into LDS (coalesced),
//     gather via ds_read_b128 (~12cyc/wave-instr, no line-tag cost).
//     Else: block-uniform fallback to direct global gather (identical math).
// Weight-0 (invalid) samples clamp into the staged region: value don't-care.
// ---------------------------------------------------------------------------
__global__ __launch_bounds__(256, 2) void cv_main(
    const _Float16* __restrict__ srcT,   // [K,H,W,C] fp16
    const _Float16* __restrict__ curT,   // [H,W,C]   fp16
    const float* __restrict__ depths,    // [D]
    const float* __restrict__ Mg,        // [K,12]
    float* __restrict__ out) {           // [D,H,W]
    __shared__ v8h tile[LDS_V8H];        // 40960 B
    const int bx  = blockIdx.x;          // 0..767
    const int rem = bx % 192;            // 16 wb x 12 hb
    const int db2 = bx / 192;            // 4 depth super-blocks
    const int t   = threadIdx.x;
    const int wx = t & 7, hy = (t >> 3) & 7, dd = t >> 6;
    const int w0 = (rem & 15) * 8, h0 = (rem >> 4) * 8;
    const int w = w0 + wx, h = h0 + hy;
    const int dbase = db2 * 16 + dd * 4;

    const float px = w + 0.5f;
    const float py = h + 0.5f;
    float dpt[4];
#pragma unroll
    for (int j = 0; j < 4; ++j) dpt[j] = depths[dbase + j];
    const float d_lo = depths[db2 * 16], d_hi = depths[db2 * 16 + 15];

    const v8h* cp = (const v8h*)(curT + (h * CV_W + w) * CV_C);
    const v8h c0 = cp[0], c1 = cp[1];

    float acc[4] = {0.f, 0.f, 0.f, 0.f};
#pragma unroll 1
    for (int k = 0; k < CV_K; ++k) {
        const float* Mk = Mg + k * 12;
        const float qx = Mk[0] * px + Mk[1] * py + Mk[2];
        const float qy = Mk[3] * px + Mk[4] * py + Mk[5];
        const float qz = Mk[6] * px + Mk[7] * py + Mk[8];
        const float bxk = Mk[9], byk = Mk[10], bzk = Mk[11];
        const v8h* sv = (const v8h*)srcT + (size_t)k * (CV_HW * 2);

        // --- (1) bbox of 8 corner projections (redundant in every thread) ---
        float umin = 1e30f, umax = -1e30f, vmin = 1e30f, vmax = -1e30f;
        float czmin = 1e30f;
#pragma unroll
        for (int ci = 0; ci < 8; ++ci) {
            float cpx = (ci & 1) ? (w0 + 7.5f) : (w0 + 0.5f);
            float cpy = (ci & 2) ? (h0 + 7.5f) : (h0 + 0.5f);
            float dc  = (ci & 4) ? d_hi : d_lo;
            float ccx = fmaf(dc, Mk[0] * cpx + Mk[1] * cpy + Mk[2], bxk);
            float ccy = fmaf(dc, Mk[3] * cpx + Mk[4] * cpy + Mk[5], byk);
            float ccz = fmaf(dc, Mk[6] * cpx + Mk[7] * cpy + Mk[8], bzk);
            czmin = fminf(czmin, ccz);
            float ri = __builtin_amdgcn_rcpf(fmaxf(ccz, 1e-8f));
            float cu = fmaf(ccx, ri, -0.5f);
            float cv = fmaf(ccy, ri, -0.5f);
            umin = fminf(umin, cu); umax = fmaxf(umax, cu);
            vmin = fminf(vmin, cv); vmax = fmaxf(vmax, cv);
        }
        // clamp to sane range before int conversion (avoid UB on huge u/v)
        umin = fminf(fmaxf(umin, -2.0f), 200.0f);
        umax = fminf(fmaxf(umax, -2.0f), 200.0f);
        vmin = fminf(fmaxf(vmin, -2.0f), 200.0f);
        vmax = fminf(fmaxf(vmax, -2.0f), 200.0f);
        const int ox  = max(0, (int)floorf(umin) - 1);
        const int xhi = min(CV_W - 1, (int)floorf(umax) + 2);
        const int oy  = max(0, (int)floorf(vmin) - 1);
        const int yhi = min(CV_H - 1, (int)floorf(vmax) + 2);
        const int Wp = xhi - ox + 1, Hp = yhi - oy + 1;
        const int pitch = Wp * 2 + 1;           // odd pitch: rotate banks per row
        const bool ok = (czmin > 1e-6f) && (Wp > 0) && (Hp > 0) &&
                        (Hp * pitch <= LDS_V8H);

        __syncthreads();                        // LDS safe to overwrite
        if (ok) {                               // --- (2) stage band ---
            const int nch = Wp * 2;
            for (int r = (t >> 6); r < Hp; r += 4) {
                const v8h* grow = sv + ((oy + r) * CV_W + ox) * 2;
                v8h* lrow = tile + r * pitch;
                for (int q = (t & 63); q < nch; q += 64)
                    lrow[q] = grow[q];
            }
            __syncthreads();
        }
        const int bxlo = ok ? ox : 0,  bxhi = ok ? xhi : CV_W - 1;
        const int bylo = ok ? oy : 0,  byhi = ok ? yhi : CV_H - 1;
        const int rp   = ok ? pitch : CV_W * 2;
        const int obase = bylo * rp + bxlo * 2; // subtract to rebase indices

        // --- phase 1: indices + weights for 4 depths (shared math) ---
        int i00[4], i10[4], i01[4], i11[4];
        float w00[4], w10[4], w01[4], w11[4], vld[4];
#pragma unroll
        for (int j = 0; j < 4; ++j) {
            float depth = dpt[j];
            float cx = fmaf(depth, qx, bxk);
            float cy = fmaf(depth, qy, byk);
            float cz = fmaf(depth, qz, bzk);
            vld[j] = (cz > 0.f) ? 1.f : 0.f;
            float inv = __builtin_amdgcn_rcpf(fabsf(cz) + CV_EPS);
            float x = fminf(fmaxf(fmaf(cx, inv, -0.5f), -4.0f), (float)(CV_W + 3));
            float y = fminf(fmaxf(fmaf(cy, inv, -0.5f), -4.0f), (float)(CV_H + 3));
            float xf = floorf(x), yf = floorf(y);
            float wx1 = x - xf, wy1 = y - yf;
            float wx0 = 1.f - wx1, wy0 = 1.f - wy1;
            int x0 = (int)xf, y0 = (int)yf;
            int x1 = x0 + 1, y1 = y0 + 1;
            bool vx0 = (unsigned)x0 < (unsigned)CV_W;
            bool vx1 = (unsigned)x1 < (unsigned)CV_W;
            bool vy0 = (unsigned)y0 < (unsigned)CV_H;
            bool vy1 = (unsigned)y1 < (unsigned)CV_H;
            int cx0 = min(max(x0, bxlo), bxhi);
            int cx1 = min(max(x1, bxlo), bxhi);
            int r0 = min(max(y0, bylo), byhi) * rp - obase;
            int r1 = min(max(y1, bylo), byhi) * rp - obase;
            i00[j] = r0 + cx0 * 2; i10[j] = r0 + cx1 * 2;
            i01[j] = r1 + cx0 * 2; i11[j] = r1 + cx1 * 2;
            w00[j] = (vx0 && vy0) ? wx0 * wy0 : 0.f;
            w10[j] = (vx1 && vy0) ? wx1 * wy0 : 0.f;
            w01[j] = (vx0 && vy1) ? wx0 * wy1 : 0.f;
            w11[j] = (vx1 && vy1) ? wx1 * wy1 : 0.f;
        }

        // --- phase 2: gather + dot (LDS or global, block-uniform branch) ---
        if (ok) {
#pragma unroll
            for (int j = 0; j < 4; ++j) {
                v8h a00 = tile[i00[j]], b00 = tile[i00[j] + 1];
                v8h a10 = tile[i10[j]], b10 = tile[i10[j] + 1];
                v8h a01 = tile[i01[j]], b01 = tile[i01[j] + 1];
                v8h a11 = tile[i11[j]], b11 = tile[i11[j] + 1];
                float s = w00[j] * dot16h(a00, b00, c0, c1)
                        + w10[j] * dot16h(a10, b10, c0, c1)
                        + w01[j] * dot16h(a01, b01, c0, c1)
                        + w11[j] * dot16h(a11, b11, c0, c1);
                acc[j] = fmaf(vld[j], s, acc[j]);
            }
        } else {
#pragma unroll
            for (int j = 0; j < 4; ++j) {
                v8h a00 = sv[i00[j]], b00 = sv[i00[j] + 1];
                v8h a10 = sv[i10[j]], b10 = sv[i10[j] + 1];
                v8h a01 = sv[i01[j]], b01 = sv[i01[j] + 1];
                v8h a11 = sv[i11[j]], b11 = sv[i11[j] + 1];
                float s = w00[j] * dot16h(a00, b00, c0, c1)
                        + w10[j] * dot16h(a10, b10, c0, c1)
                        + w01[j] * dot16h(a01, b01, c0, c1)
                        + w11[j] * dot16h(a11, b11, c0, c1);
                acc[j] = fmaf(vld[j], s, acc[j]);
            }
        }
    }
#pragma unroll
    for (int j = 0; j < 4; ++j)
        out[((dbase + j) * CV_H + h) * CV_W + w] = acc[j];
}

extern "C" void kernel_launch(void* const* d_in, const int* in_sizes, int n_in,
                              void* d_out, int out_size, void* d_ws, size_t ws_size,
                              hipStream_t stream) {
    const float* cur_feats = (const float*)d_in[0];  // [1,16,96,128]
    const float* src_feats = (const float*)d_in[1];  // [1,7,16,96,128]
    const float* extr      = (const float*)d_in[2];  // [1,7,4,4]
    // d_in[3] = src_poses (unused)
    const float* Ks        = (const float*)d_in[4];  // [1,7,4,4]
    const float* invK      = (const float*)d_in[5];  // [1,4,4]
    const float* minD      = (const float*)d_in[6];
    const float* maxD      = (const float*)d_in[7];
    float* out = (float*)d_out;

    float* wsf    = (float*)d_ws;
    float* depths = wsf;                       // 64 floats
    float* M      = wsf + 64;                  // 84 floats
    _Float16* srcT = (_Float16*)(wsf + 256);   // [7,96,128,16] fp16
    _Float16* curT = srcT + (size_t)CV_K * CV_HW * CV_C;

    cv_prep<<<(CV_K + 1) * CV_H + 1, 256, 0, stream>>>(
        cur_feats, src_feats, extr, Ks, invK, minD, maxD, depths, M, srcT, curT);

    cv_main<<<(CV_D / 16) * (CV_H / 8) * (CV_W / 8), 256, 0, stream>>>(
        srcT, curT, depths, M, out);
}

// Round 8
// 32.696 us; speedup vs baseline: 1.1961x; 1.1961x over previous
//
#include <hip/hip_runtime.h>

#define CV_H 96
#define CV_W 128
#define CV_C 16
#define CV_K 7
#define CV_D 64
#define CV_EPS 1e-8f
#define CV_HW (CV_H * CV_W)

typedef _Float16 v2h __attribute__((ext_vector_type(2)));
typedef _Float16 v8h __attribute__((ext_vector_type(8)));

#if __has_builtin(__builtin_amdgcn_fdot2)
#define FDOT2(a, b, c) __builtin_amdgcn_fdot2((a), (b), (c), false)
#else
#define FDOT2(a, b, c) ((float)(a)[0] * (float)(b)[0] + (float)(a)[1] * (float)(b)[1] + (c))
#endif

// ---------------------------------------------------------------------------
// Prep: blocks 0..(K+1)*H-1 LDS-transpose one (view,row) [C=16][W=128] f32
// into PLANE-SPLIT fp16: srcA[k,h,w]=ch0..7 (16B), srcB[k,h,w]=ch8..15 (16B).
// (cur stays interleaved [h,w,16] - its loads are wave-uniform-coalesced.)
// Last block: depth planes + fused projection matrices M[k]=[A|b];
// cam = depth*(A@[x+.5,y+.5,1]) + b.
// ---------------------------------------------------------------------------
__global__ __launch_bounds__(256) void cv_prep(
    const float* __restrict__ cur, const float* __restrict__ src,
    const float* __restrict__ extr, const float* __restrict__ Ks,
    const float* __restrict__ invK, const float* __restrict__ minD,
    const float* __restrict__ maxD,
    float* __restrict__ depths, float* __restrict__ M,
    v8h* __restrict__ srcA, v8h* __restrict__ srcB,
    _Float16* __restrict__ curT) {
    const int b = blockIdx.x;
    if (b == (CV_K + 1) * CV_H) {            // tiny setup block
        int t = threadIdx.x;
        if (t < CV_D) {
            float mn = minD[0], mx = maxD[0];
            float ramp = (float)t * (1.0f / (CV_D - 1));
            depths[t] = expf(logf(mn) + logf(mx / mn) * ramp);
        }
        if (t < CV_K) {
            const float* Km = Ks + t * 16;
            const float* E  = extr + t * 16;
            float P[3][4];
            for (int i = 0; i < 3; ++i)
                for (int j = 0; j < 4; ++j) {
                    float s = 0.f;
                    for (int l = 0; l < 4; ++l) s += Km[i * 4 + l] * E[l * 4 + j];
                    P[i][j] = s;
                }
            float* Mk = M + t * 12;
            for (int i = 0; i < 3; ++i)
                for (int j = 0; j < 3; ++j) {
                    float s = 0.f;
                    for (int l = 0; l < 3; ++l) s += P[i][l] * invK[l * 4 + j];
                    Mk[i * 3 + j] = s;
                }
            for (int i = 0; i < 3; ++i) Mk[9 + i] = P[i][3];
        }
        return;
    }
    const int g = b / CV_H;                  // 0..6 src views, 7 = cur
    const int h = b % CV_H;
    const float* rowBase = (g < CV_K) ? (src + (size_t)g * CV_C * CV_HW + h * CV_W)
                                      : (cur + h * CV_W);
    __shared__ float lds[CV_C][CV_W + 2];
    const int t = threadIdx.x;
#pragma unroll
    for (int i = 0; i < 2; ++i) {
        int f  = t + i * 256;                // float4 id, 0..511
        int c  = f >> 5;
        int w4 = (f & 31) << 2;
        float4 v = *(const float4*)(rowBase + (size_t)c * CV_HW + w4);
        lds[c][w4 + 0] = v.x; lds[c][w4 + 1] = v.y;
        lds[c][w4 + 2] = v.z; lds[c][w4 + 3] = v.w;
    }
    __syncthreads();
    const int p  = t >> 1;                   // pixel 0..127
    const int hf = t & 1;                    // channel half
    const int cb = hf << 3;
    v8h o;
#pragma unroll
    for (int j = 0; j < 8; ++j) o[j] = (_Float16)lds[cb + j][p];
    if (g < CV_K) {
        const size_t i = (size_t)g * CV_HW + h * CV_W + p;
        if (hf == 0) srcA[i] = o; else srcB[i] = o;
    } else {
        *(v8h*)(curT + ((size_t)h * CV_W + p) * CV_C + cb) = o;
    }
}

__device__ __forceinline__ float dot16h(v8h a0, v8h a1, v8h b0, v8h b1) {
    const v2h* pa0 = (const v2h*)&a0; const v2h* pb0 = (const v2h*)&b0;
    const v2h* pa1 = (const v2h*)&a1; const v2h* pb1 = (const v2h*)&b1;
    float s = 0.f;
#pragma unroll
    for (int i = 0; i < 4; ++i) s = FDOT2(pa0[i], pb0[i], s);
#pragma unroll
    for (int i = 0; i < 4; ++i) s = FDOT2(pa1[i], pb1[i], s);
    return s;
}

// ---------------------------------------------------------------------------
// Main (R5 structure + plane-split gathers): block = 8x8 px tile x 16
// depths, 4 depths/thread.  Per corner: one 16B load from srcA + one from
// srcB (each plane 16B/pixel -> wave footprint in 64B lines halves vs the
// 32B interleaved record; TA line-tag processing is the measured limiter).
// ---------------------------------------------------------------------------
__global__ __launch_bounds__(256, 2) void cv_main(
    const v8h* __restrict__ srcA,        // [K,H,W] ch0..7
    const v8h* __restrict__ srcB,        // [K,H,W] ch8..15
    const _Float16* __restrict__ curT,   // [H,W,C]
    const float* __restrict__ depths,    // [D]
    const float* __restrict__ Mg,        // [K,12]
    float* __restrict__ out) {           // [D,H,W]
    const int bx  = blockIdx.x;          // 0..767
    const int rem = bx % 192;            // 16 wb x 12 hb
    const int db2 = bx / 192;            // 4 depth super-blocks
    const int t   = threadIdx.x;
    const int wx = t & 7, hy = (t >> 3) & 7, dd = t >> 6;
    const int w = (rem & 15) * 8 + wx;
    const int h = (rem >> 4) * 8 + hy;
    const int dbase = db2 * 16 + dd * 4; // this thread: depths dbase..dbase+3

    const float px = w + 0.5f;
    const float py = h + 0.5f;
    float dpt[4];
#pragma unroll
    for (int j = 0; j < 4; ++j) dpt[j] = depths[dbase + j];

    const v8h* cp = (const v8h*)(curT + (h * CV_W + w) * CV_C);
    const v8h c0 = cp[0], c1 = cp[1];

    float acc[4] = {0.f, 0.f, 0.f, 0.f};
#pragma unroll
    for (int k = 0; k < CV_K; ++k) {
        const float* Mk = Mg + k * 12;
        const float qx = Mk[0] * px + Mk[1] * py + Mk[2];
        const float qy = Mk[3] * px + Mk[4] * py + Mk[5];
        const float qz = Mk[6] * px + Mk[7] * py + Mk[8];
        const float bxk = Mk[9], byk = Mk[10], bzk = Mk[11];
        const v8h* pA = srcA + (size_t)k * CV_HW;
        const v8h* pB = srcB + (size_t)k * CV_HW;
#pragma unroll
        for (int j = 0; j < 4; ++j) {
            float depth = dpt[j];
            float cx = fmaf(depth, qx, bxk);
            float cy = fmaf(depth, qy, byk);
            float cz = fmaf(depth, qz, bzk);
            float valid = (cz > 0.f) ? 1.f : 0.f;        // z>0 mask
            float inv = __builtin_amdgcn_rcpf(fabsf(cz) + CV_EPS);
            float x = fminf(fmaxf(fmaf(cx, inv, -0.5f), -4.0f), (float)(CV_W + 3));
            float y = fminf(fmaxf(fmaf(cy, inv, -0.5f), -4.0f), (float)(CV_H + 3));
            float xf = floorf(x), yf = floorf(y);
            float wx1 = x - xf, wy1 = y - yf;
            float wx0 = 1.f - wx1, wy0 = 1.f - wy1;
            int x0 = (int)xf, y0 = (int)yf;
            int x1 = x0 + 1, y1 = y0 + 1;
            bool vx0 = (unsigned)x0 < (unsigned)CV_W;
            bool vx1 = (unsigned)x1 < (unsigned)CV_W;
            bool vy0 = (unsigned)y0 < (unsigned)CV_H;
            bool vy1 = (unsigned)y1 < (unsigned)CV_H;
            int cx0 = min(max(x0, 0), CV_W - 1);
            int cx1 = min(max(x1, 0), CV_W - 1);
            int r0 = min(max(y0, 0), CV_H - 1) * CV_W;
            int r1 = min(max(y1, 0), CV_H - 1) * CV_W;
            int i00 = r0 + cx0, i10 = r0 + cx1;
            int i01 = r1 + cx0, i11 = r1 + cx1;
            v8h a00 = pA[i00], b00 = pB[i00];
            v8h a10 = pA[i10], b10 = pB[i10];
            v8h a01 = pA[i01], b01 = pB[i01];
            v8h a11 = pA[i11], b11 = pB[i11];
            float w00 = (vx0 && vy0) ? wx0 * wy0 : 0.f;
            float w10 = (vx1 && vy0) ? wx1 * wy0 : 0.f;
            float w01 = (vx0 && vy1) ? wx0 * wy1 : 0.f;
            float w11 = (vx1 && vy1) ? wx1 * wy1 : 0.f;
            float s = w00 * dot16h(a00, b00, c0, c1)
                    + w10 * dot16h(a10, b10, c0, c1)
                    + w01 * dot16h(a01, b01, c0, c1)
                    + w11 * dot16h(a11, b11, c0, c1);
            acc[j] = fmaf(valid, s, acc[j]);
        }
    }
#pragma unroll
    for (int j = 0; j < 4; ++j)
        out[((dbase + j) * CV_H + h) * CV_W + w] = acc[j];
}

extern "C" void kernel_launch(void* const* d_in, const int* in_sizes, int n_in,
                              void* d_out, int out_size, void* d_ws, size_t ws_size,
                              hipStream_t stream) {
    const float* cur_feats = (const float*)d_in[0];  // [1,16,96,128]
    const float* src_feats = (const float*)d_in[1];  // [1,7,16,96,128]
    const float* extr      = (const float*)d_in[2];  // [1,7,4,4]
    // d_in[3] = src_poses (unused)
    const float* Ks        = (const float*)d_in[4];  // [1,7,4,4]
    const float* invK      = (const float*)d_in[5];  // [1,4,4]
    const float* minD      = (const float*)d_in[6];
    const float* maxD      = (const float*)d_in[7];
    float* out = (float*)d_out;

    float* wsf    = (float*)d_ws;
    float* depths = wsf;                                    // 64 floats
    float* M      = wsf + 64;                               // 84 floats
    v8h* srcA = (v8h*)(wsf + 256);                          // [7*HW] 16B recs
    v8h* srcB = srcA + (size_t)CV_K * CV_HW;                // [7*HW]
    _Float16* curT = (_Float16*)(srcB + (size_t)CV_K * CV_HW);  // [HW*16]

    cv_prep<<<(CV_K + 1) * CV_H + 1, 256, 0, stream>>>(
        cur_feats, src_feats, extr, Ks, invK, minD, maxD, depths, M,
        srcA, srcB, curT);

    cv_main<<<(CV_D / 16) * (CV_H / 8) * (CV_W / 8), 256, 0, stream>>>(
        srcA, srcB, curT, depths, M, out);
}